// Round 4
// baseline (303.602 us; speedup 1.0000x reference)
//
#include <hip/hip_runtime.h>
#include <math.h>

#define N_TOK 65536
#define DIM   512
#define HID   102
#define KTOK  64
#define NBLK  2048          // total 32-token tiles
#define TILES 2             // tiles per scorer block
#define LN_EPS 1e-5f

typedef __attribute__((ext_vector_type(8))) short short8;
typedef __attribute__((ext_vector_type(4))) float f32x4;

// ws layout (float offsets)
#define WS_LOGITS 0u
#define WS_PART   4194304u                 // 128*64*512
#define WS_PM     (WS_PART + 4194304u)     // 2048*64
#define WS_PS     (WS_PM + 131072u)        // 2048*64
#define WS_W1F    (WS_PS + 131072u)        // 65536 ushort (packed frags)
#define WS_W2F    (WS_W1F + 32768u)        // 8192 ushort (packed frags)
#define WS_B1P    (WS_W2F + 4096u)
#define WS_SMAX   (WS_B1P + 128u)
#define WS_SINV   (WS_SMAX + 64u)

__device__ __forceinline__ unsigned short f2bf(float f) {
    unsigned int u = __float_as_uint(f);
    unsigned int r = (u + 0x7fffu + ((u >> 16) & 1u)) >> 16;
    return (unsigned short)r;
}

// LDS-only barrier: does NOT drain vmcnt -> global prefetches stay in flight.
__device__ __forceinline__ void bar_lds() {
    asm volatile("s_waitcnt lgkmcnt(0)" ::: "memory");
    __builtin_amdgcn_s_barrier();
    __builtin_amdgcn_sched_barrier(0);
}

// ---------------- prep: weights packed in MFMA-fragment order ----------------
// W1f[((J*16+kc)*64+lane)*8+e] = W1[d][j], j=J*16+(lane&15), d=kc*32+(lane>>4)*8+e
// W2f[((N*4 +kc)*64+lane)*8+e] = W2[j][k], k=N*16+(lane&15), j=kc*32+(lane>>4)*8+e
__global__ __launch_bounds__(256) void prep_k(const float* __restrict__ W1,
                                              const float* __restrict__ b1,
                                              const float* __restrict__ W2,
                                              unsigned short* __restrict__ W1f,
                                              unsigned short* __restrict__ W2f,
                                              float* __restrict__ b1p) {
    const int idx = blockIdx.x * 256 + threadIdx.x;   // 0..65535
    {
        const int e = idx & 7, lane = (idx >> 3) & 63;
        const int kc = (idx >> 9) & 15, J = (idx >> 13) & 7;
        const int j = J * 16 + (lane & 15);
        const int d = kc * 32 + (lane >> 4) * 8 + e;
        W1f[idx] = (j < HID) ? f2bf(W1[d * HID + j]) : (unsigned short)0;
    }
    if (idx < 8192) {
        const int e = idx & 7, lane = (idx >> 3) & 63;
        const int kc = (idx >> 9) & 3, N = (idx >> 11) & 3;
        const int j = kc * 32 + (lane >> 4) * 8 + e;
        const int k = N * 16 + (lane & 15);
        W2f[idx] = (j < HID) ? f2bf(W2[j * KTOK + k]) : (unsigned short)0;
    }
    if (idx < 128) b1p[idx] = (idx < HID) ? b1[idx] : 0.0f;
}

// ------- scorer: persistent 2-tile pipeline, LN + fc1 + GELU + fc2 + partials -------
__global__ __launch_bounds__(256, 4) void scorer_k(const float* __restrict__ x,
                                                   const float* __restrict__ gamma,
                                                   const float* __restrict__ beta,
                                                   const unsigned short* __restrict__ W1f,
                                                   const unsigned short* __restrict__ W2f,
                                                   const float* __restrict__ b1p,
                                                   const float* __restrict__ b2,
                                                   const float* __restrict__ scale,
                                                   float* __restrict__ logits,
                                                   float* __restrict__ pm,
                                                   float* __restrict__ psum) {
    __shared__ char smem[32 * 1024 + 8 * 1024];
    char* xs = smem;                         // [32 rows][1024 B] bf16, XOR-swizzled
    char* hsm = smem + 32 * 1024;            // [32 rows][256 B] bf16, XOR-swizzled
    float* lt = (float*)smem;                // [64 k][32 tok] fp32, aliases xs

    const int tid = threadIdx.x;
    const int lane = tid & 63;
    const int w = tid >> 6;
    const int l15 = lane & 15;
    const int hi = lane >> 4;
    const int tg = w & 1;       // token group (16 rows)
    const int hf = w >> 1;      // hidden/k half

    const f32x4 g0 = *(const f32x4*)&gamma[lane * 8];
    const f32x4 g1 = *(const f32x4*)&gamma[lane * 8 + 4];
    const f32x4 be0 = *(const f32x4*)&beta[lane * 8];
    const f32x4 be1 = *(const f32x4*)&beta[lane * 8 + 4];

    // preload tile 0 x rows (8 rows/wave, 32B/lane/row)
    f32x4 xr[8][2];
    {
        const float* xb = x + ((size_t)blockIdx.x * TILES * 32 + w * 8) * DIM + lane * 8;
        #pragma unroll
        for (int r = 0; r < 8; ++r) {
            xr[r][0] = *(const f32x4*)(xb + r * DIM);
            xr[r][1] = *(const f32x4*)(xb + r * DIM + 4);
        }
    }

    for (int t = 0; t < TILES; ++t) {
        const int tile = blockIdx.x * TILES + t;
        const int n0 = tile * 32;

        // ---- LayerNorm from regs -> xs (two 4-row groups for shfl ILP) ----
        #pragma unroll
        for (int rr = 0; rr < 2; ++rr) {
            float s[4], ss[4];
            #pragma unroll
            for (int r = 0; r < 4; ++r) {
                const f32x4 a = xr[rr * 4 + r][0], b = xr[rr * 4 + r][1];
                s[r] = a.x + a.y + a.z + a.w + b.x + b.y + b.z + b.w;
                ss[r] = a.x * a.x + a.y * a.y + a.z * a.z + a.w * a.w +
                        b.x * b.x + b.y * b.y + b.z * b.z + b.w * b.w;
            }
            #pragma unroll
            for (int o = 32; o >= 1; o >>= 1) {
                #pragma unroll
                for (int r = 0; r < 4; ++r) {
                    s[r] += __shfl_xor(s[r], o);
                    ss[r] += __shfl_xor(ss[r], o);
                }
            }
            #pragma unroll
            for (int r = 0; r < 4; ++r) {
                const int row = w * 8 + rr * 4 + r;
                const f32x4 a = xr[rr * 4 + r][0], b = xr[rr * 4 + r][1];
                const float mu = s[r] * (1.0f / 512.0f);
                const float inv = rsqrtf(ss[r] * (1.0f / 512.0f) - mu * mu + LN_EPS);
                short8 v;
                v[0] = (short)f2bf((a.x - mu) * inv * g0.x + be0.x);
                v[1] = (short)f2bf((a.y - mu) * inv * g0.y + be0.y);
                v[2] = (short)f2bf((a.z - mu) * inv * g0.z + be0.z);
                v[3] = (short)f2bf((a.w - mu) * inv * g0.w + be0.w);
                v[4] = (short)f2bf((b.x - mu) * inv * g1.x + be1.x);
                v[5] = (short)f2bf((b.y - mu) * inv * g1.y + be1.y);
                v[6] = (short)f2bf((b.z - mu) * inv * g1.z + be1.z);
                v[7] = (short)f2bf((b.w - mu) * inv * g1.w + be1.w);
                *(short8*)(xs + row * 1024 + ((lane * 16) ^ ((row & 7) << 4))) = v;
            }
        }
        bar_lds();   // A: xs ready

        // ---- fc1: tokens tg*16..+16 x hidden half hf, B double-buffered ----
        {
            const int arow = tg * 16 + l15;
            const char* abase = xs + arow * 1024;
            const int asw = (arow & 7) << 4;
            const unsigned short* wf = W1f + (size_t)(hf * 4) * 16 * 512 + lane * 8;
            f32x4 acc[4] = {};
            short8 bc[4], bn[4];
            #pragma unroll
            for (int jj = 0; jj < 4; ++jj)
                bc[jj] = *(const short8*)(wf + (size_t)jj * 16 * 512);
            #pragma unroll
            for (int kc = 0; kc < 16; ++kc) {
                if (kc < 15) {
                    #pragma unroll
                    for (int jj = 0; jj < 4; ++jj)
                        bn[jj] = *(const short8*)(wf + ((size_t)jj * 16 + kc + 1) * 512);
                }
                const short8 a = *(const short8*)(abase + ((kc * 64 + hi * 16) ^ asw));
                #pragma unroll
                for (int jj = 0; jj < 4; ++jj)
                    acc[jj] = __builtin_amdgcn_mfma_f32_16x16x32_bf16(a, bc[jj], acc[jj], 0, 0, 0);
                #pragma unroll
                for (int jj = 0; jj < 4; ++jj) bc[jj] = bn[jj];
            }
            #pragma unroll
            for (int jj = 0; jj < 4; ++jj) {
                const int col = hf * 64 + jj * 16 + l15;
                const float bias = b1p[col];
                #pragma unroll
                for (int reg = 0; reg < 4; ++reg) {
                    const int row = tg * 16 + 4 * hi + reg;
                    const float tt = acc[jj][reg] + bias;
                    const float g = 0.5f * tt * (1.0f + erff(tt * 0.70710678118f));
                    *(unsigned short*)(hsm + row * 256 + ((col * 2) ^ ((row & 7) << 4))) =
                        f2bf(g);
                }
            }
        }
        bar_lds();   // B: hs ready

        // ---- prefetch next tile's x (overlaps fc2+store+next-LN compute) ----
        if (t + 1 < TILES) {
            const float* xn = x + ((size_t)(n0 + 32) + w * 8) * DIM + lane * 8;
            #pragma unroll
            for (int r = 0; r < 8; ++r) {
                xr[r][0] = *(const f32x4*)(xn + r * DIM);
                xr[r][1] = *(const f32x4*)(xn + r * DIM + 4);
            }
        }

        // ---- fc2: tokens tg*16..+16 x k-half hf ----
        {
            const int arow = tg * 16 + l15;
            const char* hbase = hsm + arow * 256;
            const int hsw = (arow & 7) << 4;
            f32x4 acc2[2] = {};
            #pragma unroll
            for (int kc = 0; kc < 4; ++kc) {
                const short8 a = *(const short8*)(hbase + ((kc * 64 + hi * 16) ^ hsw));
                #pragma unroll
                for (int nt = 0; nt < 2; ++nt) {
                    const short8 b = *(const short8*)(W2f +
                        (((size_t)(hf * 2 + nt) * 4 + kc) * 64 + lane) * 8);
                    acc2[nt] = __builtin_amdgcn_mfma_f32_16x16x32_bf16(a, b, acc2[nt], 0, 0, 0);
                }
            }
            const float sc = scale[0];
            #pragma unroll
            for (int nt = 0; nt < 2; ++nt) {
                const int k = (hf * 2 + nt) * 16 + l15;
                const float bb = b2[k];
                const int ksw = (k & 7) << 4;
                #pragma unroll
                for (int reg = 0; reg < 4; ++reg) {
                    const int token = tg * 16 + 4 * hi + reg;
                    *(float*)((char*)lt + k * 128 + ((token * 4) ^ ksw)) =
                        (acc2[nt][reg] + bb) * sc;
                }
            }
        }
        bar_lds();   // C: lt ready

        // ---- logits store + per-tile softmax partials ----
        {
            const int k = tid >> 2, q = tid & 3;
            const int ksw = (k & 7) << 4;
            const char* lrow = (const char*)lt + k * 128;
            const f32x4 v0 = *(const f32x4*)(lrow + ((q * 32) ^ ksw));
            const f32x4 v1 = *(const f32x4*)(lrow + ((q * 32 + 16) ^ ksw));
            float* dst = logits + (size_t)k * N_TOK + n0 + q * 8;
            *(f32x4*)dst = v0;
            *(f32x4*)(dst + 4) = v1;
            float m8 = fmaxf(fmaxf(fmaxf(v0.x, v0.y), fmaxf(v0.z, v0.w)),
                             fmaxf(fmaxf(v1.x, v1.y), fmaxf(v1.z, v1.w)));
            float s8 = __expf(v0.x - m8) + __expf(v0.y - m8) + __expf(v0.z - m8) +
                       __expf(v0.w - m8) + __expf(v1.x - m8) + __expf(v1.y - m8) +
                       __expf(v1.z - m8) + __expf(v1.w - m8);
            #pragma unroll
            for (int o = 1; o <= 2; o <<= 1) {
                const float om = __shfl_xor(m8, o);
                const float os = __shfl_xor(s8, o);
                const float nm = fmaxf(m8, om);
                s8 = s8 * __expf(m8 - nm) + os * __expf(om - nm);
                m8 = nm;
            }
            if (q == 0) {
                pm[tile * 64 + k] = m8;
                psum[tile * 64 + k] = s8;
            }
        }
        bar_lds();   // D: protect xs/lt reuse next tile
    }
}

// ---------------- stats: combine per-tile partials ----------------
__global__ __launch_bounds__(256) void stats_k(const float* __restrict__ pm,
                                               const float* __restrict__ psum,
                                               float* __restrict__ smax,
                                               float* __restrict__ sinv) {
    const int k = blockIdx.x;
    const int tid = threadIdx.x;
    __shared__ float rm[4], rs[4];
    float m = -1e30f, s = 0.0f;
    for (int b = tid; b < NBLK; b += 256) {
        const float pmv = pm[b * 64 + k];
        const float psv = psum[b * 64 + k];
        const float nm = fmaxf(m, pmv);
        s = s * __expf(m - nm) + psv * __expf(pmv - nm);
        m = nm;
    }
    #pragma unroll
    for (int o = 32; o >= 1; o >>= 1) {
        const float om = __shfl_xor(m, o);
        const float os = __shfl_xor(s, o);
        const float nm = fmaxf(m, om);
        s = s * __expf(m - nm) + os * __expf(om - nm);
        m = nm;
    }
    if ((tid & 63) == 0) { rm[tid >> 6] = m; rs[tid >> 6] = s; }
    __syncthreads();
    if (tid == 0) {
        float fm = rm[0], fs = rs[0];
        for (int i = 1; i < 4; ++i) {
            const float nm = fmaxf(fm, rm[i]);
            fs = fs * __expf(fm - nm) + rs[i] * __expf(rm[i] - nm);
            fm = nm;
        }
        smax[k] = fm;
        sinv[k] = 1.0f / fs;
    }
}

// ---------------- agg: double-buffered ps, 1 barrier/chunk ----------------
__global__ __launch_bounds__(512, 4) void agg_k(const float* __restrict__ x,
                                                const float* __restrict__ logits,
                                                const float* __restrict__ smax,
                                                const float* __restrict__ sinv,
                                                float* __restrict__ part) {
    __shared__ float ps[2][64][65];
    const int tid = threadIdx.x;
    const int dg = blockIdx.y;
    const int tb = blockIdx.x;
    const int kq = tid >> 5;            // 0..15 -> k = kq*4..+4
    const int dt = tid & 31;
    const int dbase = dg * 128 + dt * 4;
    const int n_start = tb * 512;
    const int sk = tid >> 3;            // staging: k row 0..63
    const int np = (tid & 7) * 8;       // staging: 8 tokens
    const float mk = smax[sk];
    const float ik = sinv[sk];
    const float* lrow = logits + (size_t)sk * N_TOK + n_start + np;
    float acc[4][4] = {};

    f32x4 va = *(const f32x4*)(lrow);
    f32x4 vb = *(const f32x4*)(lrow + 4);

    for (int c = 0; c < 8; ++c) {
        const int cur = c & 1;
        float* pr = &ps[cur][sk][np];
        pr[0] = __expf(va.x - mk) * ik;
        pr[1] = __expf(va.y - mk) * ik;
        pr[2] = __expf(va.z - mk) * ik;
        pr[3] = __expf(va.w - mk) * ik;
        pr[4] = __expf(vb.x - mk) * ik;
        pr[5] = __expf(vb.y - mk) * ik;
        pr[6] = __expf(vb.z - mk) * ik;
        pr[7] = __expf(vb.w - mk) * ik;
        bar_lds();
        if (c < 7) {
            va = *(const f32x4*)(lrow + (c + 1) * 64);
            vb = *(const f32x4*)(lrow + (c + 1) * 64 + 4);
        }
        const int n0 = n_start + c * 64;
        #pragma unroll 4
        for (int n = 0; n < 64; ++n) {
            const f32x4 xv = *(const f32x4*)&x[(size_t)(n0 + n) * DIM + dbase];
            #pragma unroll
            for (int i = 0; i < 4; ++i) {
                const float p = ps[cur][kq * 4 + i][n];
                acc[i][0] = fmaf(p, xv.x, acc[i][0]);
                acc[i][1] = fmaf(p, xv.y, acc[i][1]);
                acc[i][2] = fmaf(p, xv.z, acc[i][2]);
                acc[i][3] = fmaf(p, xv.w, acc[i][3]);
            }
        }
    }
    #pragma unroll
    for (int i = 0; i < 4; ++i) {
        const int k = kq * 4 + i;
        f32x4 v;
        v.x = acc[i][0]; v.y = acc[i][1]; v.z = acc[i][2]; v.w = acc[i][3];
        *(f32x4*)&part[((size_t)tb * 64 + k) * 512 + dbase] = v;
    }
}

// ---------------- reduce: out[k][d] = sum_tb part[tb][k][d] ----------------
__global__ __launch_bounds__(256) void reduce_k(const float* __restrict__ part,
                                                float* __restrict__ out) {
    const int idx = blockIdx.x * 256 + threadIdx.x;  // 0..32767
    const int k = idx >> 9, d = idx & 511;
    float s = 0.0f;
    for (int tb = 0; tb < 128; ++tb) s += part[((size_t)tb * 64 + k) * 512 + d];
    out[idx] = s;
}

extern "C" void kernel_launch(void* const* d_in, const int* in_sizes, int n_in,
                              void* d_out, int out_size, void* d_ws, size_t ws_size,
                              hipStream_t stream) {
    const float* x     = (const float*)d_in[0];
    const float* gamma = (const float*)d_in[1];
    const float* beta  = (const float*)d_in[2];
    const float* W1    = (const float*)d_in[3];
    const float* b1    = (const float*)d_in[4];
    const float* W2    = (const float*)d_in[5];
    const float* b2    = (const float*)d_in[6];
    const float* scale = (const float*)d_in[7];
    float* out = (float*)d_out;
    float* ws  = (float*)d_ws;

    float* logits = ws + WS_LOGITS;
    float* part   = ws + WS_PART;
    float* pm     = ws + WS_PM;
    float* psum   = ws + WS_PS;
    unsigned short* W1f = (unsigned short*)(ws + WS_W1F);
    unsigned short* W2f = (unsigned short*)(ws + WS_W2F);
    float* b1p  = ws + WS_B1P;
    float* smax = ws + WS_SMAX;
    float* sinv = ws + WS_SINV;

    hipLaunchKernelGGL(prep_k, dim3(256), dim3(256), 0, stream,
                       W1, b1, W2, W1f, W2f, b1p);
    hipLaunchKernelGGL(scorer_k, dim3(NBLK / TILES), dim3(256), 0, stream,
                       x, gamma, beta, W1f, W2f, b1p, b2, scale, logits, pm, psum);
    hipLaunchKernelGGL(stats_k, dim3(KTOK), dim3(256), 0, stream,
                       pm, psum, smax, sinv);
    hipLaunchKernelGGL(agg_k, dim3(128, 4), dim3(512), 0, stream,
                       x, logits, smax, sinv, part);
    hipLaunchKernelGGL(reduce_k, dim3(128), dim3(256), 0, stream,
                       part, out);
}

// Round 5
// 184.831 us; speedup vs baseline: 1.6426x; 1.6426x over previous
//
#include <hip/hip_runtime.h>
#include <math.h>

#define N_TOK 65536
#define DIM   512
#define HID   102
#define KTOK  64
#define NTILE 4096          // 16-token tiles
#define LN_EPS 1e-5f

typedef __attribute__((ext_vector_type(8))) short short8;
typedef __attribute__((ext_vector_type(4))) float f32x4;

// ws layout (float offsets)
#define WS_LOGITS 0u
#define WS_PART   4194304u                 // 128*64*512
#define WS_PM     (WS_PART + 4194304u)     // 4096*64
#define WS_PS     (WS_PM + 262144u)        // 4096*64
#define WS_W1F    (WS_PS + 262144u)        // 65536 ushort (packed frags)
#define WS_W2F    (WS_W1F + 32768u)        // 8192 ushort (packed frags)
#define WS_B1P    (WS_W2F + 4096u)
#define WS_SMAX   (WS_B1P + 128u)
#define WS_SINV   (WS_SMAX + 64u)

__device__ __forceinline__ unsigned short f2bf(float f) {
    unsigned int u = __float_as_uint(f);
    unsigned int r = (u + 0x7fffu + ((u >> 16) & 1u)) >> 16;
    return (unsigned short)r;
}

// ---------------- prep: weights packed in MFMA-fragment order ----------------
// W1f[((J*16+kc)*64+lane)*8+e] = W1[d][j], j=J*16+(lane&15), d=kc*32+(lane>>4)*8+e
// W2f[((N*4 +kc)*64+lane)*8+e] = W2[j][k], k=N*16+(lane&15), j=kc*32+(lane>>4)*8+e
__global__ __launch_bounds__(256) void prep_k(const float* __restrict__ W1,
                                              const float* __restrict__ b1,
                                              const float* __restrict__ W2,
                                              unsigned short* __restrict__ W1f,
                                              unsigned short* __restrict__ W2f,
                                              float* __restrict__ b1p) {
    const int idx = blockIdx.x * 256 + threadIdx.x;   // 0..65535
    {
        const int e = idx & 7, lane = (idx >> 3) & 63;
        const int kc = (idx >> 9) & 15, J = (idx >> 13) & 7;
        const int j = J * 16 + (lane & 15);
        const int d = kc * 32 + (lane >> 4) * 8 + e;
        W1f[idx] = (j < HID) ? f2bf(W1[d * HID + j]) : (unsigned short)0;
    }
    if (idx < 8192) {
        const int e = idx & 7, lane = (idx >> 3) & 63;
        const int kc = (idx >> 9) & 3, N = (idx >> 11) & 3;
        const int j = kc * 32 + (lane >> 4) * 8 + e;
        const int k = N * 16 + (lane & 15);
        W2f[idx] = (j < HID) ? f2bf(W2[j * KTOK + k]) : (unsigned short)0;
    }
    if (idx < 128) b1p[idx] = (idx < HID) ? b1[idx] : 0.0f;
}

// ------- scorer: barrier-free, one 16-token tile per wave -------
__global__ __launch_bounds__(256) void scorer_k(const float* __restrict__ x,
                                                const float* __restrict__ gamma,
                                                const float* __restrict__ beta,
                                                const unsigned short* __restrict__ W1f,
                                                const unsigned short* __restrict__ W2f,
                                                const float* __restrict__ b1p,
                                                const float* __restrict__ b2,
                                                const float* __restrict__ scale,
                                                float* __restrict__ logits,
                                                float* __restrict__ pm,
                                                float* __restrict__ psum) {
    __shared__ char hsm[4][16 * 256];   // per-wave h bounce, 16 KB total
    const int tid = threadIdx.x;
    const int lane = tid & 63;
    const int w = tid >> 6;
    const int l15 = lane & 15;
    const int hi = lane >> 4;
    const int tile = blockIdx.x * 4 + w;
    const int wt0 = tile * 16;
    char* hb = &hsm[w][0];

    // ---- LN pass 1: full-row sums, 2-shfl reduce (4 lanes share a row) ----
    const float* xrow = x + (size_t)(wt0 + l15) * DIM + hi * 8;
    float s = 0.0f, ss = 0.0f;
    #pragma unroll
    for (int kc = 0; kc < 16; ++kc) {
        const f32x4 a = *(const f32x4*)(xrow + kc * 32);
        const f32x4 b = *(const f32x4*)(xrow + kc * 32 + 4);
        s += a.x + a.y + a.z + a.w + b.x + b.y + b.z + b.w;
        ss += a.x * a.x + a.y * a.y + a.z * a.z + a.w * a.w +
              b.x * b.x + b.y * b.y + b.z * b.z + b.w * b.w;
        if ((kc & 3) == 3) __builtin_amdgcn_sched_barrier(0);
    }
    s += __shfl_xor(s, 16); ss += __shfl_xor(ss, 16);
    s += __shfl_xor(s, 32); ss += __shfl_xor(ss, 32);
    const float mu = s * (1.0f / 512.0f);
    const float inv = rsqrtf(ss * (1.0f / 512.0f) - mu * mu + LN_EPS);

    asm volatile("" : "+v"(xrow));   // launder: force reload (stop CSE->spill)

    // ---- LN pass 2: normalize+pack straight into A-fragments ----
    short8 nx[16];
    #pragma unroll
    for (int kc = 0; kc < 16; ++kc) {
        const f32x4 a = *(const f32x4*)(xrow + kc * 32);
        const f32x4 b = *(const f32x4*)(xrow + kc * 32 + 4);
        const f32x4 g0 = *(const f32x4*)(gamma + kc * 32 + hi * 8);
        const f32x4 g1 = *(const f32x4*)(gamma + kc * 32 + hi * 8 + 4);
        const f32x4 e0 = *(const f32x4*)(beta + kc * 32 + hi * 8);
        const f32x4 e1 = *(const f32x4*)(beta + kc * 32 + hi * 8 + 4);
        short8 v;
        v[0] = (short)f2bf((a.x - mu) * inv * g0.x + e0.x);
        v[1] = (short)f2bf((a.y - mu) * inv * g0.y + e0.y);
        v[2] = (short)f2bf((a.z - mu) * inv * g0.z + e0.z);
        v[3] = (short)f2bf((a.w - mu) * inv * g0.w + e0.w);
        v[4] = (short)f2bf((b.x - mu) * inv * g1.x + e1.x);
        v[5] = (short)f2bf((b.y - mu) * inv * g1.y + e1.y);
        v[6] = (short)f2bf((b.z - mu) * inv * g1.z + e1.z);
        v[7] = (short)f2bf((b.w - mu) * inv * g1.w + e1.w);
        nx[kc] = v;
        if ((kc & 3) == 3) __builtin_amdgcn_sched_barrier(0);
    }

    // ---- fc1: 16 tokens x 128 hidden, explicit 2-stage B prefetch ----
    f32x4 acc[8] = {};
    {
        const unsigned short* wf = W1f + lane * 8;
        short8 bc[8], bn[8];
        #pragma unroll
        for (int jj = 0; jj < 8; ++jj)
            bc[jj] = *(const short8*)(wf + (size_t)jj * 8192);
        #pragma unroll
        for (int kc = 0; kc < 16; ++kc) {
            if (kc < 15) {
                #pragma unroll
                for (int jj = 0; jj < 8; ++jj)
                    bn[jj] = *(const short8*)(wf + (size_t)jj * 8192 + (kc + 1) * 512);
            }
            __builtin_amdgcn_s_setprio(1);
            #pragma unroll
            for (int jj = 0; jj < 8; ++jj)
                acc[jj] = __builtin_amdgcn_mfma_f32_16x16x32_bf16(nx[kc], bc[jj], acc[jj], 0, 0, 0);
            __builtin_amdgcn_s_setprio(0);
            #pragma unroll
            for (int jj = 0; jj < 8; ++jj) bc[jj] = bn[jj];
        }
    }

    // ---- bias + GELU -> wave-private LDS (swizzled bf16) ----
    #pragma unroll
    for (int jj = 0; jj < 8; ++jj) {
        const int col = jj * 16 + l15;
        const float bias = b1p[col];
        #pragma unroll
        for (int reg = 0; reg < 4; ++reg) {
            const int t = 4 * hi + reg;
            const float tt = acc[jj][reg] + bias;
            const float g = 0.5f * tt * (1.0f + erff(tt * 0.70710678118f));
            *(unsigned short*)(hb + t * 256 + ((col * 2) ^ ((t & 7) << 4))) = f2bf(g);
        }
    }
    asm volatile("s_waitcnt lgkmcnt(0)" ::: "memory");
    __builtin_amdgcn_sched_barrier(0);

    // ---- fc2: 16 tokens x 64 k ----
    f32x4 acc2[4] = {};
    {
        const unsigned short* w2 = W2f + lane * 8;
        #pragma unroll
        for (int kc = 0; kc < 4; ++kc) {
            const short8 a2 = *(const short8*)(hb + l15 * 256 +
                                               ((kc * 64 + hi * 16) ^ ((l15 & 7) << 4)));
            __builtin_amdgcn_s_setprio(1);
            #pragma unroll
            for (int nt = 0; nt < 4; ++nt) {
                const short8 bfr = *(const short8*)(w2 + (size_t)(nt * 4 + kc) * 512);
                acc2[nt] = __builtin_amdgcn_mfma_f32_16x16x32_bf16(a2, bfr, acc2[nt], 0, 0, 0);
            }
            __builtin_amdgcn_s_setprio(0);
        }
    }

    // ---- logits store (16B/lane contiguous) + per-tile softmax partials ----
    const float sc = scale[0];
    #pragma unroll
    for (int nt = 0; nt < 4; ++nt) {
        const int k = nt * 16 + l15;
        const float bb = b2[k];
        f32x4 lv;
        lv.x = (acc2[nt][0] + bb) * sc;
        lv.y = (acc2[nt][1] + bb) * sc;
        lv.z = (acc2[nt][2] + bb) * sc;
        lv.w = (acc2[nt][3] + bb) * sc;
        *(f32x4*)(logits + (size_t)k * N_TOK + wt0 + hi * 4) = lv;
        float m4 = fmaxf(fmaxf(lv.x, lv.y), fmaxf(lv.z, lv.w));
        float s4 = __expf(lv.x - m4) + __expf(lv.y - m4) +
                   __expf(lv.z - m4) + __expf(lv.w - m4);
        #pragma unroll
        for (int o = 16; o <= 32; o <<= 1) {
            const float om = __shfl_xor(m4, o);
            const float os = __shfl_xor(s4, o);
            const float nm = fmaxf(m4, om);
            s4 = s4 * __expf(m4 - nm) + os * __expf(om - nm);
            m4 = nm;
        }
        if (hi == 0) {
            pm[tile * 64 + k] = m4;
            psum[tile * 64 + k] = s4;
        }
    }
}

// ---------------- stats: combine per-tile partials ----------------
__global__ __launch_bounds__(256) void stats_k(const float* __restrict__ pm,
                                               const float* __restrict__ psum,
                                               float* __restrict__ smax,
                                               float* __restrict__ sinv) {
    const int k = blockIdx.x;
    const int tid = threadIdx.x;
    __shared__ float rm[4], rs[4];
    float m = -1e30f, s = 0.0f;
    for (int b = tid; b < NTILE; b += 256) {
        const float pmv = pm[b * 64 + k];
        const float psv = psum[b * 64 + k];
        const float nm = fmaxf(m, pmv);
        s = s * __expf(m - nm) + psv * __expf(pmv - nm);
        m = nm;
    }
    #pragma unroll
    for (int o = 32; o >= 1; o >>= 1) {
        const float om = __shfl_xor(m, o);
        const float os = __shfl_xor(s, o);
        const float nm = fmaxf(m, om);
        s = s * __expf(m - nm) + os * __expf(om - nm);
        m = nm;
    }
    if ((tid & 63) == 0) { rm[tid >> 6] = m; rs[tid >> 6] = s; }
    __syncthreads();
    if (tid == 0) {
        float fm = rm[0], fs = rs[0];
        for (int i = 1; i < 4; ++i) {
            const float nm = fmaxf(fm, rm[i]);
            fs = fs * __expf(fm - nm) + rs[i] * __expf(rm[i] - nm);
            fm = nm;
        }
        smax[k] = fm;
        sinv[k] = 1.0f / fs;
    }
}

// ---------------- agg: partial[tb][k][d], 512 tokens/block (R3-proven) ----------------
__global__ __launch_bounds__(512, 4) void agg_k(const float* __restrict__ x,
                                                const float* __restrict__ logits,
                                                const float* __restrict__ smax,
                                                const float* __restrict__ sinv,
                                                float* __restrict__ part) {
    __shared__ float ps[64][65];
    const int tid = threadIdx.x;
    const int dg = blockIdx.y;
    const int tb = blockIdx.x;
    const int kq = tid >> 5;            // 0..15 -> k = kq*4..+4
    const int dt = tid & 31;
    const int dbase = dg * 128 + dt * 4;
    const int n_start = tb * 512;
    const int sk = tid >> 3;            // staging: k row 0..63
    const int np = (tid & 7) * 8;       // staging: 8 tokens
    const float mk = smax[sk];
    const float ik = sinv[sk];
    float acc[4][4] = {};

    for (int c = 0; c < 8; ++c) {
        const int n0 = n_start + c * 64;
        const f32x4 va = *(const f32x4*)&logits[(size_t)sk * N_TOK + n0 + np];
        const f32x4 vb = *(const f32x4*)&logits[(size_t)sk * N_TOK + n0 + np + 4];
        __syncthreads();
        ps[sk][np + 0] = __expf(va.x - mk) * ik;
        ps[sk][np + 1] = __expf(va.y - mk) * ik;
        ps[sk][np + 2] = __expf(va.z - mk) * ik;
        ps[sk][np + 3] = __expf(va.w - mk) * ik;
        ps[sk][np + 4] = __expf(vb.x - mk) * ik;
        ps[sk][np + 5] = __expf(vb.y - mk) * ik;
        ps[sk][np + 6] = __expf(vb.z - mk) * ik;
        ps[sk][np + 7] = __expf(vb.w - mk) * ik;
        __syncthreads();
        #pragma unroll 4
        for (int n = 0; n < 64; ++n) {
            const f32x4 xv = *(const f32x4*)&x[(size_t)(n0 + n) * DIM + dbase];
            #pragma unroll
            for (int i = 0; i < 4; ++i) {
                const float p = ps[kq * 4 + i][n];
                acc[i][0] = fmaf(p, xv.x, acc[i][0]);
                acc[i][1] = fmaf(p, xv.y, acc[i][1]);
                acc[i][2] = fmaf(p, xv.z, acc[i][2]);
                acc[i][3] = fmaf(p, xv.w, acc[i][3]);
            }
        }
    }
    #pragma unroll
    for (int i = 0; i < 4; ++i) {
        const int k = kq * 4 + i;
        f32x4 v;
        v.x = acc[i][0]; v.y = acc[i][1]; v.z = acc[i][2]; v.w = acc[i][3];
        *(f32x4*)&part[((size_t)tb * 64 + k) * 512 + dbase] = v;
    }
}

// ---------------- reduce: out[k][d] = sum_tb part[tb][k][d] ----------------
__global__ __launch_bounds__(256) void reduce_k(const float* __restrict__ part,
                                                float* __restrict__ out) {
    const int idx = blockIdx.x * 256 + threadIdx.x;  // 0..32767
    const int k = idx >> 9, d = idx & 511;
    float s = 0.0f;
    for (int tb = 0; tb < 128; ++tb) s += part[((size_t)tb * 64 + k) * 512 + d];
    out[idx] = s;
}

extern "C" void kernel_launch(void* const* d_in, const int* in_sizes, int n_in,
                              void* d_out, int out_size, void* d_ws, size_t ws_size,
                              hipStream_t stream) {
    const float* x     = (const float*)d_in[0];
    const float* gamma = (const float*)d_in[1];
    const float* beta  = (const float*)d_in[2];
    const float* W1    = (const float*)d_in[3];
    const float* b1    = (const float*)d_in[4];
    const float* W2    = (const float*)d_in[5];
    const float* b2    = (const float*)d_in[6];
    const float* scale = (const float*)d_in[7];
    float* out = (float*)d_out;
    float* ws  = (float*)d_ws;

    float* logits = ws + WS_LOGITS;
    float* part   = ws + WS_PART;
    float* pm     = ws + WS_PM;
    float* psum   = ws + WS_PS;
    unsigned short* W1f = (unsigned short*)(ws + WS_W1F);
    unsigned short* W2f = (unsigned short*)(ws + WS_W2F);
    float* b1p  = ws + WS_B1P;
    float* smax = ws + WS_SMAX;
    float* sinv = ws + WS_SINV;

    hipLaunchKernelGGL(prep_k, dim3(256), dim3(256), 0, stream,
                       W1, b1, W2, W1f, W2f, b1p);
    hipLaunchKernelGGL(scorer_k, dim3(NTILE / 4), dim3(256), 0, stream,
                       x, gamma, beta, W1f, W2f, b1p, b2, scale, logits, pm, psum);
    hipLaunchKernelGGL(stats_k, dim3(KTOK), dim3(256), 0, stream,
                       pm, psum, smax, sinv);
    hipLaunchKernelGGL(agg_k, dim3(128, 4), dim3(512), 0, stream,
                       x, logits, smax, sinv, part);
    hipLaunchKernelGGL(reduce_k, dim3(128), dim3(256), 0, stream,
                       part, out);
}